// Round 20
// baseline (352.869 us; speedup 1.0000x reference)
//
#include <hip/hip_runtime.h>
#include <cstdint>
#include <cstddef>

#define TPB 256

// fp32 -> bf16 (round to nearest even), as raw ushort
__device__ __forceinline__ unsigned short f2bf(float f) {
  unsigned u = __float_as_uint(f);
  u += 0x7fffu + ((u >> 16) & 1u);
  return (unsigned short)(u >> 16);
}
__device__ __forceinline__ float bf_lo(unsigned u) { return __uint_as_float(u << 16); }
__device__ __forceinline__ float bf_hi(unsigned u) { return __uint_as_float(u & 0xffff0000u); }

#define FIXP32 8192.0f        // 2^13 fixed-point for weighted degree (20-bit field)
#define DEGMASK 0xFFFFFu      // low 20 bits

typedef __attribute__((ext_vector_type(8))) short  short8v;   // 8 bf16 (4 VGPRs)
typedef __attribute__((ext_vector_type(4))) float  float4v;   // MFMA acc

// ---------------- GEMM device body (fused edges|gemm1 + standalone) ----------

template<int COUT, bool RELU, bool BF16IN>
__device__ __forceinline__ void gemm_body(int bid, const void* __restrict__ Xv,
                                          const unsigned short* __restrict__ Wt,
                                          unsigned short* __restrict__ H, int n) {
  const int lane = threadIdx.x & 63;
  const int wv   = threadIdx.x >> 6;             // 0..3
  const int r0   = (bid * 4 + wv) * 16;          // wave's row strip
  if (r0 >= n) return;
  const int c16   = lane & 15;
  const int kb    = (lane >> 4) * 8;             // 0,8,16,24
  const int row_c = min(r0 + c16, n - 1);        // clamp OOB loads

  short8v a[4];
  if (BF16IN) {
    const unsigned short* xrow = (const unsigned short*)Xv + (size_t)row_c * 128;
    #pragma unroll
    for (int kk = 0; kk < 4; kk++) {
      short8v t = *(const short8v*)(xrow + kk * 32 + kb);
      if (RELU) {
        #pragma unroll
        for (int j = 0; j < 8; j++) t[j] = (short)(t[j] & 0x8000) ? (short)0 : t[j];
      }
      a[kk] = t;
    }
  } else {
    const float* xrow = (const float*)Xv + (size_t)row_c * 128;
    #pragma unroll
    for (int kk = 0; kk < 4; kk++) {
      float4 lo = *(const float4*)(xrow + kk * 32 + kb);
      float4 hi = *(const float4*)(xrow + kk * 32 + kb + 4);
      float v0 = lo.x, v1 = lo.y, v2 = lo.z, v3 = lo.w;
      float v4 = hi.x, v5 = hi.y, v6 = hi.z, v7 = hi.w;
      if (RELU) {
        v0 = fmaxf(v0, 0.f); v1 = fmaxf(v1, 0.f); v2 = fmaxf(v2, 0.f); v3 = fmaxf(v3, 0.f);
        v4 = fmaxf(v4, 0.f); v5 = fmaxf(v5, 0.f); v6 = fmaxf(v6, 0.f); v7 = fmaxf(v7, 0.f);
      }
      short8v t;
      t[0] = (short)f2bf(v0); t[1] = (short)f2bf(v1);
      t[2] = (short)f2bf(v2); t[3] = (short)f2bf(v3);
      t[4] = (short)f2bf(v4); t[5] = (short)f2bf(v5);
      t[6] = (short)f2bf(v6); t[7] = (short)f2bf(v7);
      a[kk] = t;
    }
  }

  constexpr int CT = COUT / 16;
  const int orow = r0 + (lane >> 4) * 4;
  #pragma unroll
  for (int ct = 0; ct < CT; ct++) {
    float4v acc = {0.f, 0.f, 0.f, 0.f};
    const unsigned short* wrow = Wt + (size_t)(ct * 16 + c16) * 128 + kb;
    #pragma unroll
    for (int kk = 0; kk < 4; kk++) {
      short8v b = *(const short8v*)(wrow + kk * 32);
      acc = __builtin_amdgcn_mfma_f32_16x16x32_bf16(a[kk], b, acc, 0, 0, 0);
    }
    const int ocol = ct * 16 + c16;
    #pragma unroll
    for (int r = 0; r < 4; r++) {
      if (orow + r < n)
        H[(size_t)(orow + r) * COUT + ocol] = f2bf(acc[r]);
    }
  }
}

// ---------------- fused: edges (atomic CSR histogram) | gemm layer-1 ----------------
// INTERLEAVED 4:1, one gemm tile per slot (R17/R19 measured best: fused ~90us).

__global__ __launch_bounds__(256) void fused_edges_gemm1(
    const int* __restrict__ ei, const float* __restrict__ w,
    unsigned* __restrict__ pk, int* __restrict__ pir, int E, int eb,
    const float* __restrict__ X, const unsigned short* __restrict__ Wt,
    unsigned short* __restrict__ H, int n, int gb) {
  const int q = blockIdx.x / 5;
  const int r = blockIdx.x % 5;
  if (r < 4) {
    int eid = q * 4 + r;
    if (eid >= eb) return;
    int e = eid * TPB + threadIdx.x;
    if (e >= E) return;
    int d = ei[E + e];
    unsigned v = (1u << 20) | (unsigned)(w[e] * FIXP32 + 0.5f);
    unsigned old = atomicAdd(&pk[d], v);
    pir[e] = (int)(old >> 20);
  } else {
    if (q >= gb) return;
    gemm_body<128, false, false>(q, X, Wt, H, n);
  }
}

// scan_a also unpacks pk -> dinv (merged unpack_k; one fewer N-pass)
__global__ void scan_a(const unsigned* __restrict__ pk, float* __restrict__ dinv,
                       int* __restrict__ rp, int* __restrict__ bsum, int n) {
  __shared__ int s[TPB];
  int i = blockIdx.x * TPB + threadIdx.x;
  unsigned pv = (i < n) ? pk[i] : 0u;
  if (i < n)
    dinv[i] = rsqrtf(1.0f + (float)(pv & DEGMASK) * (1.0f / FIXP32));  // self-loop => deg>=1
  int v = (int)(pv >> 20);
  s[threadIdx.x] = v;
  __syncthreads();
  #pragma unroll
  for (int off = 1; off < TPB; off <<= 1) {
    int t = (threadIdx.x >= off) ? s[threadIdx.x - off] : 0;
    __syncthreads();
    s[threadIdx.x] += t;
    __syncthreads();
  }
  if (i < n) rp[i] = s[threadIdx.x] - v;            // exclusive within block
  if (threadIdx.x == TPB - 1) bsum[blockIdx.x] = s[TPB - 1];
}

__global__ void scan_b(int* __restrict__ bsum, int nb) {
  __shared__ int s[512];
  int v = (threadIdx.x < nb) ? bsum[threadIdx.x] : 0;
  s[threadIdx.x] = v;
  __syncthreads();
  #pragma unroll
  for (int off = 1; off < 512; off <<= 1) {
    int t = (threadIdx.x >= off) ? s[threadIdx.x - off] : 0;
    __syncthreads();
    s[threadIdx.x] += t;
    __syncthreads();
  }
  if (threadIdx.x < nb) bsum[threadIdx.x] = s[threadIdx.x] - v;  // exclusive block offsets
}

__global__ void scan_c(int* __restrict__ rp, const int* __restrict__ bsum, int n, int etot) {
  int i = blockIdx.x * TPB + threadIdx.x;
  if (i < n) rp[i] += bsum[blockIdx.x];
  if (blockIdx.x == 0 && threadIdx.x == 0) rp[n] = etot;
}

// no atomic: slot comes from pir[] captured by the packed atomic
__global__ void fill_k(const int* __restrict__ ei, const float* __restrict__ w,
                       const float* __restrict__ dinv, const int* __restrict__ rp,
                       const int* __restrict__ pir, int2* __restrict__ epk, int E) {
  int e = blockIdx.x * TPB + threadIdx.x;
  if (e >= E) return;
  int s = ei[e];
  int d = ei[E + e];
  int pos = rp[d] + pir[e];
  float nrm = dinv[s] * w[e] * dinv[d];
  epk[pos] = make_int2(s, __float_as_int(nrm));
}

// transpose + bf16-convert all three weight matrices: wtX[c][k] = W[k][c]
__global__ void wt_k(const float* __restrict__ W1, const float* __restrict__ W2,
                     const float* __restrict__ W3,
                     unsigned short* __restrict__ wt1, unsigned short* __restrict__ wt2,
                     unsigned short* __restrict__ wt3) {
  int t = blockIdx.x * TPB + threadIdx.x;
  if (t < 16384) {                  // W1 128x128
    int c = t >> 7, k = t & 127;
    wt1[t] = f2bf(W1[k * 128 + c]);
  } else if (t < 32768) {           // W2 128x128
    int u = t - 16384;
    int c = u >> 7, k = u & 127;
    wt2[u] = f2bf(W2[k * 128 + c]);
  } else if (t < 40960) {           // W3 128x64
    int u = t - 32768;
    int c = u >> 7, k = u & 127;
    wt3[u] = f2bf(W3[k * 64 + c]);
  }
}

// ---------------- fused agg128 + next-layer GEMM ----------------
// Block = 4 waves, 16 consecutive nodes. Each wave aggregates 4 nodes (same
// 16-deep-MLP gather loops as agg128), packs bf16 into a 16x136-padded LDS
// tile (272B row stride: 16B-aligned, 2-way bank alias = free), syncs, then
// the 4 waves split the 16-row MFMA gemm across column tiles. Activations
// never touch HBM. Output buffer MUST differ from gather table (ping-pong).

#define ASTRIDE 136   // shorts per LDS row

template<int COUT>
__global__ __launch_bounds__(256) void agg_gemm(const unsigned short* __restrict__ H,
                                                const int* __restrict__ rp,
                                                const int2* __restrict__ epk,
                                                const float* __restrict__ dinv,
                                                const float* __restrict__ bias,
                                                const unsigned short* __restrict__ Wt,
                                                unsigned short* __restrict__ Hout, int n) {
  __shared__ unsigned short As[16 * ASTRIDE];
  const int lane = threadIdx.x & 63;
  const int wv   = threadIdx.x >> 6;
  const int base = blockIdx.x * 16;
  if (base >= n) return;

  // ---- agg phase: wave wv handles nodes base+wv*4 .. +3 ----
  for (int i = 0; i < 4; i++) {
    int node = base + wv * 4 + i;
    if (node >= n) break;
    float di = dinv[node];
    float w0 = di * di;
    unsigned hv = ((const unsigned*)(H + (size_t)node * 128))[lane];
    float2 bv = ((const float2*)bias)[lane];
    float ax = bv.x + w0 * bf_lo(hv);
    float ay = bv.y + w0 * bf_hi(hv);
    int e  = rp[node];
    int e1 = rp[node + 1];
    for (; e + 15 < e1; e += 16) {
      int2 p[16];
      #pragma unroll
      for (int u = 0; u < 16; u++) p[u] = epk[e + u];
      unsigned h[16];
      #pragma unroll
      for (int u = 0; u < 16; u++) h[u] = ((const unsigned*)(H + (size_t)p[u].x * 128))[lane];
      #pragma unroll
      for (int u = 0; u < 16; u++) {
        float nw = __int_as_float(p[u].y);
        ax += nw * bf_lo(h[u]);
        ay += nw * bf_hi(h[u]);
      }
    }
    for (; e + 3 < e1; e += 4) {
      int2 p[4];
      #pragma unroll
      for (int u = 0; u < 4; u++) p[u] = epk[e + u];
      unsigned h[4];
      #pragma unroll
      for (int u = 0; u < 4; u++) h[u] = ((const unsigned*)(H + (size_t)p[u].x * 128))[lane];
      #pragma unroll
      for (int u = 0; u < 4; u++) {
        float nw = __int_as_float(p[u].y);
        ax += nw * bf_lo(h[u]);
        ay += nw * bf_hi(h[u]);
      }
    }
    for (; e < e1; e++) {
      int2 p = epk[e];
      unsigned h = ((const unsigned*)(H + (size_t)p.x * 128))[lane];
      float nw = __int_as_float(p.y);
      ax += nw * bf_lo(h); ay += nw * bf_hi(h);
    }
    // pack 2 bf16 per lane into LDS row (lanes write consecutive words: no conflict)
    unsigned pk2 = (unsigned)f2bf(ax) | ((unsigned)f2bf(ay) << 16);
    *(unsigned*)(As + (wv * 4 + i) * ASTRIDE + lane * 2) = pk2;
  }
  __syncthreads();

  // ---- gemm phase: 16 rows (LDS, ReLU on read) x 128 @ Wt -> Hout ----
  constexpr int CT  = COUT / 16;   // 8 (COUT=128) or 4 (COUT=64)
  constexpr int TPW = CT / 4;      // column tiles per wave: 2 or 1
  const int c16  = lane & 15;
  const int kb   = (lane >> 4) * 8;
  const int vrow = min(16, n - base);
  const int rrow = min(c16, vrow - 1);     // clamp A-row within tile
  short8v a[4];
  #pragma unroll
  for (int kk = 0; kk < 4; kk++) {
    short8v t = *(const short8v*)(As + rrow * ASTRIDE + kk * 32 + kb);
    #pragma unroll
    for (int j = 0; j < 8; j++) t[j] = (short)(t[j] & 0x8000) ? (short)0 : t[j];  // ReLU
    a[kk] = t;
  }
  const int orow0 = base + (lane >> 4) * 4;
  #pragma unroll
  for (int tt = 0; tt < TPW; tt++) {
    const int ct = wv * TPW + tt;
    float4v acc = {0.f, 0.f, 0.f, 0.f};
    const unsigned short* wrow = Wt + (size_t)(ct * 16 + c16) * 128 + kb;
    #pragma unroll
    for (int kk = 0; kk < 4; kk++) {
      short8v b = *(const short8v*)(wrow + kk * 32);
      acc = __builtin_amdgcn_mfma_f32_16x16x32_bf16(a[kk], b, acc, 0, 0, 0);
    }
    const int ocol = ct * 16 + c16;
    #pragma unroll
    for (int r = 0; r < 4; r++) {
      if (orow0 + r < n)
        Hout[(size_t)(orow0 + r) * COUT + ocol] = f2bf(acc[r]);
    }
  }
}

// ---------------- final aggregation (64ch, fp32 out) ----------------

__global__ __launch_bounds__(256) void agg64(const unsigned short* __restrict__ H,
                                             const int* __restrict__ rp,
                                             const int2* __restrict__ epk,
                                             const float* __restrict__ dinv,
                                             const float* __restrict__ bias,
                                             float* __restrict__ OUT, int n) {
  int wid  = __builtin_amdgcn_readfirstlane(blockIdx.x * 4 + (threadIdx.x >> 6));
  int lane = threadIdx.x & 63;
  if (wid >= n) return;
  float di = dinv[wid];
  float w0 = di * di;
  float hv = __uint_as_float(((unsigned)H[(size_t)wid * 64 + lane]) << 16);
  float acc = bias[lane] + w0 * hv;
  int e  = rp[wid];
  int e1 = rp[wid + 1];
  for (; e + 15 < e1; e += 16) {
    int2 p[16];
    #pragma unroll
    for (int u = 0; u < 16; u++) p[u] = epk[e + u];
    float h[16];
    #pragma unroll
    for (int u = 0; u < 16; u++)
      h[u] = __uint_as_float(((unsigned)H[(size_t)p[u].x * 64 + lane]) << 16);
    #pragma unroll
    for (int u = 0; u < 16; u++) acc += __int_as_float(p[u].y) * h[u];
  }
  for (; e + 3 < e1; e += 4) {
    int2 p[4];
    #pragma unroll
    for (int u = 0; u < 4; u++) p[u] = epk[e + u];
    float h[4];
    #pragma unroll
    for (int u = 0; u < 4; u++)
      h[u] = __uint_as_float(((unsigned)H[(size_t)p[u].x * 64 + lane]) << 16);
    #pragma unroll
    for (int u = 0; u < 4; u++) acc += __int_as_float(p[u].y) * h[u];
  }
  for (; e < e1; e++) {
    int2 p = epk[e];
    float h = __uint_as_float(((unsigned)H[(size_t)p.x * 64 + lane]) << 16);
    acc += __int_as_float(p.y) * h;
  }
  OUT[(size_t)wid * 64 + lane] = acc;
}

// ---------------- launch ----------------

extern "C" void kernel_launch(void* const* d_in, const int* in_sizes, int n_in,
                              void* d_out, int out_size, void* d_ws, size_t ws_size,
                              hipStream_t stream) {
  const float* x  = (const float*)d_in[0];
  const int*   ei = (const int*)d_in[1];    // int64 in reference -> int32 on device
  const float* ew = (const float*)d_in[2];
  const float* W1 = (const float*)d_in[3];
  const float* b1 = (const float*)d_in[4];
  const float* W2 = (const float*)d_in[5];
  const float* b2 = (const float*)d_in[6];
  const float* W3 = (const float*)d_in[7];
  const float* b3 = (const float*)d_in[8];

  const int N = in_sizes[0] / 128;
  const int E = in_sizes[2];

  char* p = (char*)d_ws;
  auto carve = [&](size_t bytes) -> void* {
    void* r = (void*)p;
    p += (bytes + 255) & ~(size_t)255;
    return r;
  };
  unsigned* pk  = (unsigned*)carve((size_t)N * 4);
  float* dinv   = (float*)carve((size_t)N * 4);
  int*   rp     = (int*)  carve((size_t)(N + 1) * 4);
  int*   bsum   = (int*)  carve(512 * 4);
  int*   pir    = (int*)  carve((size_t)E * 4);
  int2*  epk    = (int2*) carve((size_t)E * 8);
  unsigned short* hbuf  = (unsigned short*)carve((size_t)N * 128 * 2);  // ping
  unsigned short* hbuf2 = (unsigned short*)carve((size_t)N * 128 * 2);  // pong
  unsigned short* wt1 = (unsigned short*)carve(16384 * 2);
  unsigned short* wt2 = (unsigned short*)carve(16384 * 2);
  unsigned short* wt3 = (unsigned short*)carve(8192 * 2);

  const int NB = (N + TPB - 1) / TPB;
  const int EB = (E + TPB - 1) / TPB;
  const int gemmBlocks = (N + 63) / 64;      // 4 waves x 16 rows per block
  const int agBlocks   = (N + 15) / 16;      // fused agg+gemm: 16 nodes per block
  const int aggBlocks  = (N + 3) / 4;        // final agg64

  // prep: zero pk, transpose weights, then fused interleaved {edges | gemm1}
  hipMemsetAsync(pk, 0, (size_t)N * 4, stream);
  wt_k<<<160, TPB, 0, stream>>>(W1, W2, W3, wt1, wt2, wt3);
  int periods = (EB + 3) / 4;
  if (gemmBlocks > periods) periods = gemmBlocks;
  fused_edges_gemm1<<<5 * periods + 5, TPB, 0, stream>>>(
      ei, ew, pk, pir, E, EB, x, wt1, hbuf, N, gemmBlocks);
  scan_a<<<NB, TPB, 0, stream>>>(pk, dinv, rp, bsum, N);
  scan_b<<<1, 512, 0, stream>>>(bsum, NB);
  scan_c<<<NB, TPB, 0, stream>>>(rp, bsum, N, E);
  fill_k<<<EB, TPB, 0, stream>>>(ei, ew, dinv, rp, pir, epk, E);

  // layer 1 agg + layer 2 gemm (fused): hbuf -> hbuf2 (128-wide)
  agg_gemm<128><<<agBlocks, 256, 0, stream>>>(hbuf, rp, epk, dinv, b1, wt2, hbuf2, N);

  // layer 2 agg + layer 3 gemm (fused): hbuf2 -> hbuf (64-wide)
  agg_gemm<64><<<agBlocks, 256, 0, stream>>>(hbuf2, rp, epk, dinv, b2, wt3, hbuf, N);

  // layer 3 agg: + b3 -> d_out fp32
  agg64<<<aggBlocks, 256, 0, stream>>>(hbuf, rp, epk, dinv, b3, (float*)d_out, N);
}

// Round 21
// 344.355 us; speedup vs baseline: 1.0247x; 1.0247x over previous
//
#include <hip/hip_runtime.h>
#include <cstdint>
#include <cstddef>

#define TPB 256

// fp32 -> bf16 (round to nearest even), as raw ushort
__device__ __forceinline__ unsigned short f2bf(float f) {
  unsigned u = __float_as_uint(f);
  u += 0x7fffu + ((u >> 16) & 1u);
  return (unsigned short)(u >> 16);
}
__device__ __forceinline__ float bf_lo(unsigned u) { return __uint_as_float(u << 16); }
__device__ __forceinline__ float bf_hi(unsigned u) { return __uint_as_float(u & 0xffff0000u); }

#define FIXP32 8192.0f        // 2^13 fixed-point for weighted degree (20-bit field)
#define DEGMASK 0xFFFFFu      // low 20 bits

typedef __attribute__((ext_vector_type(8))) short  short8v;   // 8 bf16 (4 VGPRs)
typedef __attribute__((ext_vector_type(4))) float  float4v;   // MFMA acc

// ---------------- GEMM device body (shared by fused + standalone kernels) ----------

template<int COUT, bool RELU, bool BF16IN>
__device__ __forceinline__ void gemm_body(int bid, const void* __restrict__ Xv,
                                          const unsigned short* __restrict__ Wt,
                                          unsigned short* __restrict__ H, int n) {
  const int lane = threadIdx.x & 63;
  const int wv   = threadIdx.x >> 6;             // 0..3
  const int r0   = (bid * 4 + wv) * 16;          // wave's row strip
  if (r0 >= n) return;
  const int c16   = lane & 15;
  const int kb    = (lane >> 4) * 8;             // 0,8,16,24
  const int row_c = min(r0 + c16, n - 1);        // clamp OOB loads

  short8v a[4];
  if (BF16IN) {
    const unsigned short* xrow = (const unsigned short*)Xv + (size_t)row_c * 128;
    #pragma unroll
    for (int kk = 0; kk < 4; kk++) {
      short8v t = *(const short8v*)(xrow + kk * 32 + kb);
      if (RELU) {
        #pragma unroll
        for (int j = 0; j < 8; j++) t[j] = (short)(t[j] & 0x8000) ? (short)0 : t[j];
      }
      a[kk] = t;
    }
  } else {
    const float* xrow = (const float*)Xv + (size_t)row_c * 128;
    #pragma unroll
    for (int kk = 0; kk < 4; kk++) {
      float4 lo = *(const float4*)(xrow + kk * 32 + kb);
      float4 hi = *(const float4*)(xrow + kk * 32 + kb + 4);
      float v0 = lo.x, v1 = lo.y, v2 = lo.z, v3 = lo.w;
      float v4 = hi.x, v5 = hi.y, v6 = hi.z, v7 = hi.w;
      if (RELU) {
        v0 = fmaxf(v0, 0.f); v1 = fmaxf(v1, 0.f); v2 = fmaxf(v2, 0.f); v3 = fmaxf(v3, 0.f);
        v4 = fmaxf(v4, 0.f); v5 = fmaxf(v5, 0.f); v6 = fmaxf(v6, 0.f); v7 = fmaxf(v7, 0.f);
      }
      short8v t;
      t[0] = (short)f2bf(v0); t[1] = (short)f2bf(v1);
      t[2] = (short)f2bf(v2); t[3] = (short)f2bf(v3);
      t[4] = (short)f2bf(v4); t[5] = (short)f2bf(v5);
      t[6] = (short)f2bf(v6); t[7] = (short)f2bf(v7);
      a[kk] = t;
    }
  }

  constexpr int CT = COUT / 16;
  const int orow = r0 + (lane >> 4) * 4;
  #pragma unroll
  for (int ct = 0; ct < CT; ct++) {
    float4v acc = {0.f, 0.f, 0.f, 0.f};
    const unsigned short* wrow = Wt + (size_t)(ct * 16 + c16) * 128 + kb;
    #pragma unroll
    for (int kk = 0; kk < 4; kk++) {
      short8v b = *(const short8v*)(wrow + kk * 32);
      acc = __builtin_amdgcn_mfma_f32_16x16x32_bf16(a[kk], b, acc, 0, 0, 0);
    }
    const int ocol = ct * 16 + c16;
    #pragma unroll
    for (int r = 0; r < 4; r++) {
      if (orow + r < n)
        H[(size_t)(orow + r) * COUT + ocol] = f2bf(acc[r]);
    }
  }
}

// ---------------- fused: edges (atomic CSR histogram) | gemm layer-1 ----------------
// INTERLEAVED 4:1, one gemm tile per slot (R17/R19 measured best: fused ~90us).

__global__ __launch_bounds__(256) void fused_edges_gemm1(
    const int* __restrict__ ei, const float* __restrict__ w,
    unsigned* __restrict__ pk, int* __restrict__ pir, int E, int eb,
    const float* __restrict__ X, const unsigned short* __restrict__ Wt,
    unsigned short* __restrict__ H, int n, int gb) {
  const int q = blockIdx.x / 5;
  const int r = blockIdx.x % 5;
  if (r < 4) {
    int eid = q * 4 + r;
    if (eid >= eb) return;
    int e = eid * TPB + threadIdx.x;
    if (e >= E) return;
    int d = ei[E + e];
    unsigned v = (1u << 20) | (unsigned)(w[e] * FIXP32 + 0.5f);
    unsigned old = atomicAdd(&pk[d], v);
    pir[e] = (int)(old >> 20);
  } else {
    if (q >= gb) return;
    gemm_body<128, false, false>(q, X, Wt, H, n);
  }
}

// scan_a also unpacks pk -> dinv (merged unpack_k; one fewer N-pass)
__global__ void scan_a(const unsigned* __restrict__ pk, float* __restrict__ dinv,
                       int* __restrict__ rp, int* __restrict__ bsum, int n) {
  __shared__ int s[TPB];
  int i = blockIdx.x * TPB + threadIdx.x;
  unsigned pv = (i < n) ? pk[i] : 0u;
  if (i < n)
    dinv[i] = rsqrtf(1.0f + (float)(pv & DEGMASK) * (1.0f / FIXP32));  // self-loop => deg>=1
  int v = (int)(pv >> 20);
  s[threadIdx.x] = v;
  __syncthreads();
  #pragma unroll
  for (int off = 1; off < TPB; off <<= 1) {
    int t = (threadIdx.x >= off) ? s[threadIdx.x - off] : 0;
    __syncthreads();
    s[threadIdx.x] += t;
    __syncthreads();
  }
  if (i < n) rp[i] = s[threadIdx.x] - v;            // exclusive within block
  if (threadIdx.x == TPB - 1) bsum[blockIdx.x] = s[TPB - 1];
}

__global__ void scan_b(int* __restrict__ bsum, int nb) {
  __shared__ int s[512];
  int v = (threadIdx.x < nb) ? bsum[threadIdx.x] : 0;
  s[threadIdx.x] = v;
  __syncthreads();
  #pragma unroll
  for (int off = 1; off < 512; off <<= 1) {
    int t = (threadIdx.x >= off) ? s[threadIdx.x - off] : 0;
    __syncthreads();
    s[threadIdx.x] += t;
    __syncthreads();
  }
  if (threadIdx.x < nb) bsum[threadIdx.x] = s[threadIdx.x] - v;  // exclusive block offsets
}

__global__ void scan_c(int* __restrict__ rp, const int* __restrict__ bsum, int n, int etot) {
  int i = blockIdx.x * TPB + threadIdx.x;
  if (i < n) rp[i] += bsum[blockIdx.x];
  if (blockIdx.x == 0 && threadIdx.x == 0) rp[n] = etot;
}

// no atomic: slot comes from pir[] captured by the packed atomic
__global__ void fill_k(const int* __restrict__ ei, const float* __restrict__ w,
                       const float* __restrict__ dinv, const int* __restrict__ rp,
                       const int* __restrict__ pir, int2* __restrict__ epk, int E) {
  int e = blockIdx.x * TPB + threadIdx.x;
  if (e >= E) return;
  int s = ei[e];
  int d = ei[E + e];
  int pos = rp[d] + pir[e];
  float nrm = dinv[s] * w[e] * dinv[d];
  epk[pos] = make_int2(s, __float_as_int(nrm));
}

// transpose + bf16-convert all three weight matrices: wtX[c][k] = W[k][c]
__global__ void wt_k(const float* __restrict__ W1, const float* __restrict__ W2,
                     const float* __restrict__ W3,
                     unsigned short* __restrict__ wt1, unsigned short* __restrict__ wt2,
                     unsigned short* __restrict__ wt3) {
  int t = blockIdx.x * TPB + threadIdx.x;
  if (t < 16384) {                  // W1 128x128
    int c = t >> 7, k = t & 127;
    wt1[t] = f2bf(W1[k * 128 + c]);
  } else if (t < 32768) {           // W2 128x128
    int u = t - 16384;
    int c = u >> 7, k = u & 127;
    wt2[u] = f2bf(W2[k * 128 + c]);
  } else if (t < 40960) {           // W3 128x64
    int u = t - 32768;
    int c = u >> 7, k = u & 127;
    wt3[u] = f2bf(W3[k * 64 + c]);
  }
}

// standalone GEMM (layers 2/3)
template<int COUT, bool RELU, bool BF16IN>
__global__ __launch_bounds__(256) void gemm_mfma(const void* __restrict__ Xv,
                                                 const unsigned short* __restrict__ Wt,
                                                 unsigned short* __restrict__ H, int n) {
  gemm_body<COUT, RELU, BF16IN>(blockIdx.x, Xv, Wt, H, n);
}

// ---------------- aggregation: one wave per node, CSR gather (bf16 table) ----------
// out[j][c] = b[c] + dinv[j]^2 * h[j][c] + sum_e norm_e * h[col_e][c]
// agg128 stores bf16 (consuming GEMM needs bf16 anyway — bit-identical).

__global__ __launch_bounds__(256) void agg128(const unsigned short* __restrict__ H,
                                              const int* __restrict__ rp,
                                              const int2* __restrict__ epk,
                                              const float* __restrict__ dinv,
                                              const float* __restrict__ bias,
                                              unsigned* __restrict__ OUT, int n) {
  int wid  = __builtin_amdgcn_readfirstlane(blockIdx.x * 4 + (threadIdx.x >> 6));
  int lane = threadIdx.x & 63;
  if (wid >= n) return;
  float di = dinv[wid];
  float w0 = di * di;
  unsigned hv = ((const unsigned*)(H + (size_t)wid * 128))[lane];
  float2 bv = ((const float2*)bias)[lane];
  float ax = bv.x + w0 * bf_lo(hv);
  float ay = bv.y + w0 * bf_hi(hv);
  int e  = rp[wid];
  int e1 = rp[wid + 1];
  for (; e + 15 < e1; e += 16) {
    int2 p[16];
    #pragma unroll
    for (int u = 0; u < 16; u++) p[u] = epk[e + u];
    unsigned h[16];
    #pragma unroll
    for (int u = 0; u < 16; u++) h[u] = ((const unsigned*)(H + (size_t)p[u].x * 128))[lane];
    #pragma unroll
    for (int u = 0; u < 16; u++) {
      float nw = __int_as_float(p[u].y);
      ax += nw * bf_lo(h[u]);
      ay += nw * bf_hi(h[u]);
    }
  }
  for (; e + 3 < e1; e += 4) {
    int2 p[4];
    #pragma unroll
    for (int u = 0; u < 4; u++) p[u] = epk[e + u];
    unsigned h[4];
    #pragma unroll
    for (int u = 0; u < 4; u++) h[u] = ((const unsigned*)(H + (size_t)p[u].x * 128))[lane];
    #pragma unroll
    for (int u = 0; u < 4; u++) {
      float nw = __int_as_float(p[u].y);
      ax += nw * bf_lo(h[u]);
      ay += nw * bf_hi(h[u]);
    }
  }
  for (; e < e1; e++) {
    int2 p = epk[e];
    unsigned h = ((const unsigned*)(H + (size_t)p.x * 128))[lane];
    float nw = __int_as_float(p.y);
    ax += nw * bf_lo(h); ay += nw * bf_hi(h);
  }
  OUT[(size_t)wid * 64 + lane] = (unsigned)f2bf(ax) | ((unsigned)f2bf(ay) << 16);
}

__global__ __launch_bounds__(256) void agg64(const unsigned short* __restrict__ H,
                                             const int* __restrict__ rp,
                                             const int2* __restrict__ epk,
                                             const float* __restrict__ dinv,
                                             const float* __restrict__ bias,
                                             float* __restrict__ OUT, int n) {
  int wid  = __builtin_amdgcn_readfirstlane(blockIdx.x * 4 + (threadIdx.x >> 6));
  int lane = threadIdx.x & 63;
  if (wid >= n) return;
  float di = dinv[wid];
  float w0 = di * di;
  float hv = __uint_as_float(((unsigned)H[(size_t)wid * 64 + lane]) << 16);
  float acc = bias[lane] + w0 * hv;
  int e  = rp[wid];
  int e1 = rp[wid + 1];
  for (; e + 15 < e1; e += 16) {
    int2 p[16];
    #pragma unroll
    for (int u = 0; u < 16; u++) p[u] = epk[e + u];
    float h[16];
    #pragma unroll
    for (int u = 0; u < 16; u++)
      h[u] = __uint_as_float(((unsigned)H[(size_t)p[u].x * 64 + lane]) << 16);
    #pragma unroll
    for (int u = 0; u < 16; u++) acc += __int_as_float(p[u].y) * h[u];
  }
  for (; e + 3 < e1; e += 4) {
    int2 p[4];
    #pragma unroll
    for (int u = 0; u < 4; u++) p[u] = epk[e + u];
    float h[4];
    #pragma unroll
    for (int u = 0; u < 4; u++)
      h[u] = __uint_as_float(((unsigned)H[(size_t)p[u].x * 64 + lane]) << 16);
    #pragma unroll
    for (int u = 0; u < 4; u++) acc += __int_as_float(p[u].y) * h[u];
  }
  for (; e < e1; e++) {
    int2 p = epk[e];
    float h = __uint_as_float(((unsigned)H[(size_t)p.x * 64 + lane]) << 16);
    acc += __int_as_float(p.y) * h;
  }
  OUT[(size_t)wid * 64 + lane] = acc;
}

// ---------------- launch ----------------

extern "C" void kernel_launch(void* const* d_in, const int* in_sizes, int n_in,
                              void* d_out, int out_size, void* d_ws, size_t ws_size,
                              hipStream_t stream) {
  const float* x  = (const float*)d_in[0];
  const int*   ei = (const int*)d_in[1];    // int64 in reference -> int32 on device
  const float* ew = (const float*)d_in[2];
  const float* W1 = (const float*)d_in[3];
  const float* b1 = (const float*)d_in[4];
  const float* W2 = (const float*)d_in[5];
  const float* b2 = (const float*)d_in[6];
  const float* W3 = (const float*)d_in[7];
  const float* b3 = (const float*)d_in[8];

  const int N = in_sizes[0] / 128;
  const int E = in_sizes[2];

  char* p = (char*)d_ws;
  auto carve = [&](size_t bytes) -> void* {
    void* r = (void*)p;
    p += (bytes + 255) & ~(size_t)255;
    return r;
  };
  unsigned* pk  = (unsigned*)carve((size_t)N * 4);
  float* dinv   = (float*)carve((size_t)N * 4);
  int*   rp     = (int*)  carve((size_t)(N + 1) * 4);
  int*   bsum   = (int*)  carve(512 * 4);
  int*   pir    = (int*)  carve((size_t)E * 4);
  int2*  epk    = (int2*) carve((size_t)E * 8);
  unsigned short* hbuf = (unsigned short*)carve((size_t)N * 128 * 2);  // bf16 gemm out
  unsigned* abuf = (unsigned*)carve((size_t)N * 128 * 2);              // bf16 agg out
  unsigned short* wt1 = (unsigned short*)carve(16384 * 2);
  unsigned short* wt2 = (unsigned short*)carve(16384 * 2);
  unsigned short* wt3 = (unsigned short*)carve(8192 * 2);

  const int NB = (N + TPB - 1) / TPB;
  const int EB = (E + TPB - 1) / TPB;
  const int aggBlocks  = (N + 3) / 4;        // one 64-lane wave per node
  const int gemmBlocks = (N + 63) / 64;      // 4 waves x 16 rows per block

  // prep: zero pk, transpose weights, then fused interleaved {edges | gemm1}
  hipMemsetAsync(pk, 0, (size_t)N * 4, stream);
  wt_k<<<160, TPB, 0, stream>>>(W1, W2, W3, wt1, wt2, wt3);
  // period-5 interleave: 4 edge blocks + 1 gemm tile per period (R17 best config)
  int periods = (EB + 3) / 4;
  if (gemmBlocks > periods) periods = gemmBlocks;
  fused_edges_gemm1<<<5 * periods + 5, TPB, 0, stream>>>(
      ei, ew, pk, pir, E, EB, x, wt1, hbuf, N, gemmBlocks);
  scan_a<<<NB, TPB, 0, stream>>>(pk, dinv, rp, bsum, N);
  scan_b<<<1, 512, 0, stream>>>(bsum, NB);
  scan_c<<<NB, TPB, 0, stream>>>(rp, bsum, N, E);
  fill_k<<<EB, TPB, 0, stream>>>(ei, ew, dinv, rp, pir, epk, E);

  // layer 1 agg: + b1 -> abuf bf16   (gemm1 already done in fused kernel)
  agg128<<<aggBlocks, 256, 0, stream>>>(hbuf, rp, epk, dinv, b1, abuf, N);

  // layer 2: h = relu(a1) @ W2 ; agg + b2 -> abuf bf16
  gemm_mfma<128, true, true><<<gemmBlocks, 256, 0, stream>>>(abuf, wt2, hbuf, N);
  agg128<<<aggBlocks, 256, 0, stream>>>(hbuf, rp, epk, dinv, b2, abuf, N);

  // layer 3: h = relu(a2) @ W3 ; agg + b3 -> d_out fp32
  gemm_mfma<64, true, true><<<gemmBlocks, 256, 0, stream>>>(abuf, wt3, hbuf, N);
  agg64<<<aggBlocks, 256, 0, stream>>>(hbuf, rp, epk, dinv, b3, (float*)d_out, N);
}